// Round 6
// baseline (635.186 us; speedup 1.0000x reference)
//
#include <hip/hip_runtime.h>
#include <math.h>

#define NPTS 4096
#define HDIM 128
#define KNN 10
#define NSPLIT 4
#define CTILE 1024
#define SLOTS 12

__device__ __forceinline__ float relu_f(float x) { return x > 0.f ? x : 0.f; }
__device__ __forceinline__ float med3_f(float a, float b, float c) {
    return __builtin_amdgcn_fmed3f(a, b, c);
}

// ---------------------------------------------------------------- KNN partial
// grid: 16 graphs x 8 query-chunks x 4 candidate-splits = 512 blocks, 256 thr.
// QPT=2: each thread owns queries i and i+256 -> one staged candidate read +
// loop overhead amortized over two med3 networks / two collects.
// Distance arithmetic bit-identical to the verified R0-R3 kernels.
__global__ __launch_bounds__(256) void knn_part(const float* __restrict__ pos,
                                                uint2* __restrict__ pdi)
{
    __shared__ float4 spt[CTILE];                      // 16 KB
    const int bid = blockIdx.x;
    const int s = bid & 3;
    const int chunk = (bid >> 2) & 7;
    const int b = bid >> 5;
    const float* pb = pos + (size_t)b * NPTS * 3;
    const int c0 = s << 10;

    for (int j = threadIdx.x; j < CTILE; j += 256) {
        int g = c0 + j;
        float x = pb[3 * g + 0], y = pb[3 * g + 1], z = pb[3 * g + 2];
        float sq = __fadd_rn(__fadd_rn(__fmul_rn(x, x), __fmul_rn(y, y)), __fmul_rn(z, z));
        spt[j] = make_float4(x, y, z, sq);
    }
    __syncthreads();

    const int i0 = chunk * 512 + threadIdx.x;
    const int i1 = i0 + 256;
    const float qx0 = pb[3 * i0 + 0], qy0 = pb[3 * i0 + 1], qz0 = pb[3 * i0 + 2];
    const float qw0 = __fadd_rn(__fadd_rn(__fmul_rn(qx0, qx0), __fmul_rn(qy0, qy0)), __fmul_rn(qz0, qz0));
    const float qx1 = pb[3 * i1 + 0], qy1 = pb[3 * i1 + 1], qz1 = pb[3 * i1 + 2];
    const float qw1 = __fadd_rn(__fadd_rn(__fmul_rn(qx1, qx1), __fmul_rn(qy1, qy1)), __fmul_rn(qz1, qz1));

    float bd0[KNN], bd1[KNN];
#pragma unroll
    for (int m = 0; m < KNN; ++m) { bd0[m] = INFINITY; bd1[m] = INFINITY; }

    // ---- pass 1: values only, two unconditional med3 networks per candidate
#pragma unroll 4
    for (int j = 0; j < CTILE; ++j) {
        float4 p = spt[j];
        float dot0 = __fadd_rn(__fadd_rn(__fmul_rn(qx0, p.x), __fmul_rn(qy0, p.y)),
                               __fmul_rn(qz0, p.z));
        float d20 = __fsub_rn(__fadd_rn(qw0, p.w), __fmul_rn(2.f, dot0));
        float dot1 = __fadd_rn(__fadd_rn(__fmul_rn(qx1, p.x), __fmul_rn(qy1, p.y)),
                               __fmul_rn(qz1, p.z));
        float d21 = __fsub_rn(__fadd_rn(qw1, p.w), __fmul_rn(2.f, dot1));
#pragma unroll
        for (int m = KNN - 1; m > 0; --m) {
            bd0[m] = med3_f(d20, bd0[m - 1], bd0[m]);
            bd1[m] = med3_f(d21, bd1[m - 1], bd1[m]);
        }
        bd0[0] = fminf(d20, bd0[0]);
        bd1[0] = fminf(d21, bd1[0]);
    }
    const float thr0 = bd0[KNN - 1];
    const float thr1 = bd1[KNN - 1];

    // ---- pass 2: collect indices with d2 <= thr (bit-identical recompute)
    uint2* o0 = pdi + ((size_t)(b * NPTS + i0) * NSPLIT + s) * SLOTS;
    uint2* o1 = pdi + ((size_t)(b * NPTS + i1) * NSPLIT + s) * SLOTS;
    int cnt0 = 0, cnt1 = 0;
#pragma unroll 4
    for (int j = 0; j < CTILE; ++j) {
        float4 p = spt[j];
        float dot0 = __fadd_rn(__fadd_rn(__fmul_rn(qx0, p.x), __fmul_rn(qy0, p.y)),
                               __fmul_rn(qz0, p.z));
        float d20 = __fsub_rn(__fadd_rn(qw0, p.w), __fmul_rn(2.f, dot0));
        float dot1 = __fadd_rn(__fadd_rn(__fmul_rn(qx1, p.x), __fmul_rn(qy1, p.y)),
                               __fmul_rn(qz1, p.z));
        float d21 = __fsub_rn(__fadd_rn(qw1, p.w), __fmul_rn(2.f, dot1));
        if (d20 <= thr0 && cnt0 < SLOTS) {
            o0[cnt0] = make_uint2(__float_as_uint(d20), (unsigned)(c0 + j));
            ++cnt0;
        }
        if (d21 <= thr1 && cnt1 < SLOTS) {
            o1[cnt1] = make_uint2(__float_as_uint(d21), (unsigned)(c0 + j));
            ++cnt1;
        }
    }
}

// ---------------------------------------------------------------- KNN merge
// 4*SLOTS candidates per query, visited split-ascending then index-ascending;
// unused slots are NaN (fail the < compare). Stable lower-index tie-break
// identical to a full scan.
__global__ __launch_bounds__(256) void knn_merge(const uint2* __restrict__ pdi,
                                                 int* __restrict__ nbr)
{
    const int q = blockIdx.x * 256 + threadIdx.x;      // 0..65535
    const uint2* in = pdi + (size_t)q * (NSPLIT * SLOTS);
    float bd[KNN];
    int   bi[KNN];
#pragma unroll
    for (int m = 0; m < KNN; ++m) { bd[m] = 3.4e38f; bi[m] = 0; }
#pragma unroll
    for (int u = 0; u < NSPLIT * SLOTS; ++u) {
        uint2 v = in[u];
        float d2 = __uint_as_float(v.x);               // NaN for unused -> all cmps false
        int   ix = (int)v.y;
        if (d2 < bd[KNN - 1]) {
            bool c[KNN];
#pragma unroll
            for (int m = 0; m < KNN; ++m) c[m] = d2 < bd[m];
#pragma unroll
            for (int m = KNN - 1; m > 0; --m) {
                bd[m] = c[m] ? (c[m - 1] ? bd[m - 1] : d2) : bd[m];
                bi[m] = c[m] ? (c[m - 1] ? bi[m - 1] : ix) : bi[m];
            }
            bd[0] = c[0] ? d2 : bd[0];
            bi[0] = c[0] ? ix : bi[0];
        }
    }
    const int b = q >> 12;
    int* o = nbr + (size_t)q * KNN;
#pragma unroll
    for (int m = 0; m < KNN; ++m) o[m] = (b << 12) + bi[m];
}

// ---------------------------------------------------------------- x0 = relu(pos@W0+b0)
__global__ __launch_bounds__(256) void x0_kernel(const float* __restrict__ pos,
                                                 const float* __restrict__ W0,
                                                 const float* __restrict__ b0,
                                                 float* __restrict__ x0)
{
    int gid = blockIdx.x * 256 + threadIdx.x;          // node*32 + quad
    int node = gid >> 5, qd = gid & 31;
    float px = pos[node * 3 + 0], py = pos[node * 3 + 1], pz = pos[node * 3 + 2];
    const float4 w0 = ((const float4*)W0)[qd];
    const float4 w1 = ((const float4*)W0)[32 + qd];
    const float4 w2 = ((const float4*)W0)[64 + qd];
    const float4 bb = ((const float4*)b0)[qd];
    float4 r;
    r.x = relu_f(fmaf(pz, w2.x, fmaf(py, w1.x, fmaf(px, w0.x, bb.x))));
    r.y = relu_f(fmaf(pz, w2.y, fmaf(py, w1.y, fmaf(px, w0.y, bb.y))));
    r.z = relu_f(fmaf(pz, w2.z, fmaf(py, w1.z, fmaf(px, w0.z, bb.z))));
    r.w = relu_f(fmaf(pz, w2.w, fmaf(py, w1.w, fmaf(px, w0.w, bb.w))));
    ((float4*)x0)[gid] = r;
}

// ---------------------------------------------------------------- fused GCN2 layer
__global__ __launch_bounds__(256) void gcn_layer(const float* __restrict__ xin,
                                                 float* __restrict__ xout,
                                                 const float* __restrict__ pos,
                                                 const float* __restrict__ W0,
                                                 const float* __restrict__ b0,
                                                 const float* __restrict__ Wl,
                                                 const int* __restrict__ nbr,
                                                 float omb, float beta)
{
    __shared__ float sh[64][129];                      // 33,024 B
    __shared__ float sW[32 * 128];                     // 16,384 B
    __shared__ float sW0[512];
    const int t = threadIdx.x;
    const int bid = blockIdx.x;
    const int swz = (bid & 7) * 128 + (bid >> 3);      // XCD-chunked, bijective
    const int node0 = swz * 64;

    if (t < 128) {
        sW0[t] = W0[t]; sW0[128 + t] = W0[128 + t];
        sW0[256 + t] = W0[256 + t]; sW0[384 + t] = b0[t];
    }
    __syncthreads();

    const float4* xin4 = (const float4*)xin;
    for (int u = t; u < 64 * 32; u += 256) {           // gather + residual -> sh
        int n = u >> 5, qd = u & 31;
        int node = node0 + n;
        float ax = 0.f, ay = 0.f, az = 0.f, aw = 0.f;
        const int* nb = nbr + node * KNN;
#pragma unroll
        for (int k = 0; k < KNN; ++k) {
            float4 v = xin4[nb[k] * 32 + qd];
            ax += v.x; ay += v.y; az += v.z; aw += v.w;
        }
        float px = pos[node * 3 + 0], py = pos[node * 3 + 1], pz = pos[node * 3 + 2];
        int c = qd * 4;
        sh[n][c + 0] = fmaf(0.9f, ax, 0.1f * relu_f(fmaf(pz, sW0[256 + c + 0], fmaf(py, sW0[128 + c + 0], fmaf(px, sW0[c + 0], sW0[384 + c + 0])))));
        sh[n][c + 1] = fmaf(0.9f, ay, 0.1f * relu_f(fmaf(pz, sW0[256 + c + 1], fmaf(py, sW0[128 + c + 1], fmaf(px, sW0[c + 1], sW0[384 + c + 1])))));
        sh[n][c + 2] = fmaf(0.9f, az, 0.1f * relu_f(fmaf(pz, sW0[256 + c + 2], fmaf(py, sW0[128 + c + 2], fmaf(px, sW0[c + 2], sW0[384 + c + 2])))));
        sh[n][c + 3] = fmaf(0.9f, aw, 0.1f * relu_f(fmaf(pz, sW0[256 + c + 3], fmaf(py, sW0[128 + c + 3], fmaf(px, sW0[c + 3], sW0[384 + c + 3])))));
    }

    const int rg = t >> 4;
    const int cq = t & 15;
    float acc[4][8];
#pragma unroll
    for (int r = 0; r < 4; ++r)
#pragma unroll
        for (int j = 0; j < 8; ++j) acc[r][j] = 0.f;

    const float4* W4 = (const float4*)Wl;
    for (int quarter = 0; quarter < 4; ++quarter) {
        __syncthreads();
        for (int u = t; u < 1024; u += 256) ((float4*)sW)[u] = W4[quarter * 1024 + u];
        __syncthreads();
#pragma unroll 4
        for (int ii = 0; ii < 32; ++ii) {
            int i = quarter * 32 + ii;
            float hv0 = sh[rg * 4 + 0][i];
            float hv1 = sh[rg * 4 + 1][i];
            float hv2 = sh[rg * 4 + 2][i];
            float hv3 = sh[rg * 4 + 3][i];
            const float4* row = (const float4*)(sW + ii * 128);
            float4 wA = row[cq];
            float4 wB = row[cq + 16];
            acc[0][0] = fmaf(hv0, wA.x, acc[0][0]); acc[0][1] = fmaf(hv0, wA.y, acc[0][1]);
            acc[0][2] = fmaf(hv0, wA.z, acc[0][2]); acc[0][3] = fmaf(hv0, wA.w, acc[0][3]);
            acc[0][4] = fmaf(hv0, wB.x, acc[0][4]); acc[0][5] = fmaf(hv0, wB.y, acc[0][5]);
            acc[0][6] = fmaf(hv0, wB.z, acc[0][6]); acc[0][7] = fmaf(hv0, wB.w, acc[0][7]);
            acc[1][0] = fmaf(hv1, wA.x, acc[1][0]); acc[1][1] = fmaf(hv1, wA.y, acc[1][1]);
            acc[1][2] = fmaf(hv1, wA.z, acc[1][2]); acc[1][3] = fmaf(hv1, wA.w, acc[1][3]);
            acc[1][4] = fmaf(hv1, wB.x, acc[1][4]); acc[1][5] = fmaf(hv1, wB.y, acc[1][5]);
            acc[1][6] = fmaf(hv1, wB.z, acc[1][6]); acc[1][7] = fmaf(hv1, wB.w, acc[1][7]);
            acc[2][0] = fmaf(hv2, wA.x, acc[2][0]); acc[2][1] = fmaf(hv2, wA.y, acc[2][1]);
            acc[2][2] = fmaf(hv2, wA.z, acc[2][2]); acc[2][3] = fmaf(hv2, wA.w, acc[2][3]);
            acc[2][4] = fmaf(hv2, wB.x, acc[2][4]); acc[2][5] = fmaf(hv2, wB.y, acc[2][5]);
            acc[2][6] = fmaf(hv2, wB.z, acc[2][6]); acc[2][7] = fmaf(hv2, wB.w, acc[2][7]);
            acc[3][0] = fmaf(hv3, wA.x, acc[3][0]); acc[3][1] = fmaf(hv3, wA.y, acc[3][1]);
            acc[3][2] = fmaf(hv3, wA.z, acc[3][2]); acc[3][3] = fmaf(hv3, wA.w, acc[3][3]);
            acc[3][4] = fmaf(hv3, wB.x, acc[3][4]); acc[3][5] = fmaf(hv3, wB.y, acc[3][5]);
            acc[3][6] = fmaf(hv3, wB.z, acc[3][6]); acc[3][7] = fmaf(hv3, wB.w, acc[3][7]);
        }
    }

#pragma unroll
    for (int r = 0; r < 4; ++r) {
        int row = rg * 4 + r;
        int node = node0 + row;
#pragma unroll
        for (int sel = 0; sel < 2; ++sel) {
            int c = cq * 4 + sel * 64;
            float4 o;
            o.x = relu_f(fmaf(omb, sh[row][c + 0], beta * acc[r][sel * 4 + 0]));
            o.y = relu_f(fmaf(omb, sh[row][c + 1], beta * acc[r][sel * 4 + 1]));
            o.z = relu_f(fmaf(omb, sh[row][c + 2], beta * acc[r][sel * 4 + 2]));
            o.w = relu_f(fmaf(omb, sh[row][c + 3], beta * acc[r][sel * 4 + 3]));
            ((float4*)(xout + (size_t)node * HDIM))[c >> 2] = o;
        }
    }
}

// ---------------------------------------------------------------- x@W1+b1 then global max-pool
__global__ __launch_bounds__(256) void w1pool_kernel(const float* __restrict__ xin,
                                                     const float* __restrict__ W1,
                                                     const float* __restrict__ b1,
                                                     unsigned int* __restrict__ pool)
{
    __shared__ float sh[64][129];
    __shared__ float sW[32 * 128];
    __shared__ float smax[16][128];
    const int t = threadIdx.x;
    const int bid = blockIdx.x;
    const int swz = (bid & 7) * 128 + (bid >> 3);
    const int node0 = swz * 64;

    const float4* xin4 = (const float4*)xin;
    for (int u = t; u < 64 * 32; u += 256) {
        int n = u >> 5, qd = u & 31;
        float4 v = xin4[(node0 + n) * 32 + qd];
        int c = qd * 4;
        sh[n][c + 0] = v.x; sh[n][c + 1] = v.y; sh[n][c + 2] = v.z; sh[n][c + 3] = v.w;
    }

    const int rg = t >> 4;
    const int cq = t & 15;
    float acc[4][8];
#pragma unroll
    for (int r = 0; r < 4; ++r)
#pragma unroll
        for (int j = 0; j < 8; ++j) acc[r][j] = 0.f;

    const float4* W4 = (const float4*)W1;
    for (int quarter = 0; quarter < 4; ++quarter) {
        __syncthreads();
        for (int u = t; u < 1024; u += 256) ((float4*)sW)[u] = W4[quarter * 1024 + u];
        __syncthreads();
#pragma unroll 4
        for (int ii = 0; ii < 32; ++ii) {
            float hv0 = sh[rg * 4 + 0][quarter * 32 + ii];
            float hv1 = sh[rg * 4 + 1][quarter * 32 + ii];
            float hv2 = sh[rg * 4 + 2][quarter * 32 + ii];
            float hv3 = sh[rg * 4 + 3][quarter * 32 + ii];
            const float4* row = (const float4*)(sW + ii * 128);
            float4 wA = row[cq];
            float4 wB = row[cq + 16];
            acc[0][0] = fmaf(hv0, wA.x, acc[0][0]); acc[0][1] = fmaf(hv0, wA.y, acc[0][1]);
            acc[0][2] = fmaf(hv0, wA.z, acc[0][2]); acc[0][3] = fmaf(hv0, wA.w, acc[0][3]);
            acc[0][4] = fmaf(hv0, wB.x, acc[0][4]); acc[0][5] = fmaf(hv0, wB.y, acc[0][5]);
            acc[0][6] = fmaf(hv0, wB.z, acc[0][6]); acc[0][7] = fmaf(hv0, wB.w, acc[0][7]);
            acc[1][0] = fmaf(hv1, wA.x, acc[1][0]); acc[1][1] = fmaf(hv1, wA.y, acc[1][1]);
            acc[1][2] = fmaf(hv1, wA.z, acc[1][2]); acc[1][3] = fmaf(hv1, wA.w, acc[1][3]);
            acc[1][4] = fmaf(hv1, wB.x, acc[1][4]); acc[1][5] = fmaf(hv1, wB.y, acc[1][5]);
            acc[1][6] = fmaf(hv1, wB.z, acc[1][6]); acc[1][7] = fmaf(hv1, wB.w, acc[1][7]);
            acc[2][0] = fmaf(hv2, wA.x, acc[2][0]); acc[2][1] = fmaf(hv2, wA.y, acc[2][1]);
            acc[2][2] = fmaf(hv2, wA.z, acc[2][2]); acc[2][3] = fmaf(hv2, wA.w, acc[2][3]);
            acc[2][4] = fmaf(hv2, wB.x, acc[2][4]); acc[2][5] = fmaf(hv2, wB.y, acc[2][5]);
            acc[2][6] = fmaf(hv2, wB.z, acc[2][6]); acc[2][7] = fmaf(hv2, wB.w, acc[2][7]);
            acc[3][0] = fmaf(hv3, wA.x, acc[3][0]); acc[3][1] = fmaf(hv3, wA.y, acc[3][1]);
            acc[3][2] = fmaf(hv3, wA.z, acc[3][2]); acc[3][3] = fmaf(hv3, wA.w, acc[3][3]);
            acc[3][4] = fmaf(hv3, wB.x, acc[3][4]); acc[3][5] = fmaf(hv3, wB.y, acc[3][5]);
            acc[3][6] = fmaf(hv3, wB.z, acc[3][6]); acc[3][7] = fmaf(hv3, wB.w, acc[3][7]);
        }
    }

#pragma unroll
    for (int sel = 0; sel < 2; ++sel) {
#pragma unroll
        for (int j = 0; j < 4; ++j) {
            int c = cq * 4 + sel * 64 + j;
            float bc = b1[c];
            float m = acc[0][sel * 4 + j] + bc;
            m = fmaxf(m, acc[1][sel * 4 + j] + bc);
            m = fmaxf(m, acc[2][sel * 4 + j] + bc);
            m = fmaxf(m, acc[3][sel * 4 + j] + bc);
            smax[rg][c] = m;
        }
    }
    __syncthreads();
    if (t < 128) {
        float m = smax[0][t];
#pragma unroll
        for (int r = 1; r < 16; ++r) m = fmaxf(m, smax[r][t]);
        unsigned int u = __float_as_uint(m);
        unsigned int key = (u & 0x80000000u) ? ~u : (u | 0x80000000u);
        atomicMax(&pool[(node0 >> 12) * HDIM + t], key);
    }
}

// ---------------------------------------------------------------- MLP head (1 block)
__global__ __launch_bounds__(256) void head_kernel(const unsigned int* __restrict__ pool,
                                                   const float* __restrict__ Wm1, const float* __restrict__ bm1,
                                                   const float* __restrict__ g1,  const float* __restrict__ be1,
                                                   const float* __restrict__ Wm2, const float* __restrict__ bm2,
                                                   const float* __restrict__ g2,  const float* __restrict__ be2,
                                                   const float* __restrict__ Wout,const float* __restrict__ bout,
                                                   float* __restrict__ out)
{
    __shared__ float sA[16][128];
    __shared__ float sB[16][128];
    __shared__ float sL[16][10];
    const int t = threadIdx.x;
    for (int u = t; u < 2048; u += 256) {
        unsigned int k = pool[u];
        unsigned int orig = (k & 0x80000000u) ? (k ^ 0x80000000u) : ~k;
        sA[u >> 7][u & 127] = __uint_as_float(orig);
    }
    __syncthreads();

    if (t < 128) {
        float y[16];
#pragma unroll
        for (int b = 0; b < 16; ++b) y[b] = bm1[t];
        for (int i = 0; i < 128; ++i) {
            float w = Wm1[i * 128 + t];
#pragma unroll
            for (int b = 0; b < 16; ++b) y[b] = fmaf(sA[b][i], w, y[b]);
        }
        float mu = 0.f;
#pragma unroll
        for (int b = 0; b < 16; ++b) mu += y[b];
        mu *= (1.f / 16.f);
        float var = 0.f;
#pragma unroll
        for (int b = 0; b < 16; ++b) { float d = y[b] - mu; var = fmaf(d, d, var); }
        var *= (1.f / 16.f);
        float sc = g1[t] / sqrtf(var + 1e-5f);
        float sb = be1[t];
#pragma unroll
        for (int b = 0; b < 16; ++b) sB[b][t] = relu_f((y[b] - mu) * sc + sb);
    }
    __syncthreads();

    if (t < 128) {
        float y[16];
#pragma unroll
        for (int b = 0; b < 16; ++b) y[b] = bm2[t];
        for (int i = 0; i < 128; ++i) {
            float w = Wm2[i * 128 + t];
#pragma unroll
            for (int b = 0; b < 16; ++b) y[b] = fmaf(sB[b][i], w, y[b]);
        }
        float mu = 0.f;
#pragma unroll
        for (int b = 0; b < 16; ++b) mu += y[b];
        mu *= (1.f / 16.f);
        float var = 0.f;
#pragma unroll
        for (int b = 0; b < 16; ++b) { float d = y[b] - mu; var = fmaf(d, d, var); }
        var *= (1.f / 16.f);
        float sc = g2[t] / sqrtf(var + 1e-5f);
        float sb = be2[t];
#pragma unroll
        for (int b = 0; b < 16; ++b) sA[b][t] = relu_f((y[b] - mu) * sc + sb);
    }
    __syncthreads();

    if (t < 160) {
        int b = t / 10, o = t % 10;
        float a = bout[o];
        for (int i = 0; i < 128; ++i) a = fmaf(sA[b][i], Wout[i * 10 + o], a);
        sL[b][o] = a;
    }
    __syncthreads();

    if (t < 16) {
        float m = sL[t][0];
#pragma unroll
        for (int o = 1; o < 10; ++o) m = fmaxf(m, sL[t][o]);
        float s = 0.f;
#pragma unroll
        for (int o = 0; o < 10; ++o) s += expf(sL[t][o] - m);
        float ls = logf(s);
#pragma unroll
        for (int o = 0; o < 10; ++o) out[t * 10 + o] = sL[t][o] - m - ls;
    }
}

// ----------------------------------------------------------------
extern "C" void kernel_launch(void* const* d_in, const int* in_sizes, int n_in,
                              void* d_out, int out_size, void* d_ws, size_t ws_size,
                              hipStream_t stream)
{
    const float* pos = (const float*)d_in[0];
    const float* W0  = (const float*)d_in[1];
    const float* b0  = (const float*)d_in[2];
    const float* Wc  = (const float*)d_in[3];
    const float* W1  = (const float*)d_in[4];
    const float* b1  = (const float*)d_in[5];
    const float* Wm1 = (const float*)d_in[6];
    const float* bm1 = (const float*)d_in[7];
    const float* g1  = (const float*)d_in[8];
    const float* be1 = (const float*)d_in[9];
    const float* Wm2 = (const float*)d_in[10];
    const float* bm2 = (const float*)d_in[11];
    const float* g2  = (const float*)d_in[12];
    const float* be2 = (const float*)d_in[13];
    const float* Wout= (const float*)d_in[14];
    const float* bout= (const float*)d_in[15];
    float* out = (float*)d_out;

    char* ws = (char*)d_ws;
    float*        xA   = (float*)ws;                       // 33,554,432 B
    float*        xB   = (float*)(ws + 33554432);          // 33,554,432 B
    int*          nbr  = (int*)(ws + 67108864);            //  2,621,440 B
    unsigned int* pool = (unsigned int*)(ws + 69730304);   //      8,192 B
    // KNN hit buffer: needed only before x0 writes xA -> alias onto xA.
    uint2* pdi = (uint2*)ws;                               // 16*4096*4*12*8 = 25,165,824 B

    hipMemsetAsync(pdi, 0xFF, (size_t)16 * NPTS * NSPLIT * SLOTS * 8, stream); // NaN prefill
    knn_part<<<512, 256, 0, stream>>>(pos, pdi);
    knn_merge<<<256, 256, 0, stream>>>(pdi, nbr);
    x0_kernel<<<8192, 256, 0, stream>>>(pos, W0, b0, xA);

    const float betas[4] = { 0.40546510810816438f, 0.22314355131420976f,
                             0.15415067982725836f, 0.11778303565638346f };
    gcn_layer<<<1024, 256, 0, stream>>>(xA, xB, pos, W0, b0, Wc + 0 * 16384, nbr, 1.f - betas[0], betas[0]);
    gcn_layer<<<1024, 256, 0, stream>>>(xB, xA, pos, W0, b0, Wc + 1 * 16384, nbr, 1.f - betas[1], betas[1]);
    gcn_layer<<<1024, 256, 0, stream>>>(xA, xB, pos, W0, b0, Wc + 2 * 16384, nbr, 1.f - betas[2], betas[2]);
    gcn_layer<<<1024, 256, 0, stream>>>(xB, xA, pos, W0, b0, Wc + 3 * 16384, nbr, 1.f - betas[3], betas[3]);

    hipMemsetAsync(pool, 0, 16 * HDIM * sizeof(unsigned int), stream);
    w1pool_kernel<<<1024, 256, 0, stream>>>(xA, W1, b1, pool);
    head_kernel<<<1, 256, 0, stream>>>(pool, Wm1, bm1, g1, be1, Wm2, bm2, g2, be2, Wout, bout, out);
}

// Round 7
// 543.015 us; speedup vs baseline: 1.1697x; 1.1697x over previous
//
#include <hip/hip_runtime.h>
#include <math.h>

#define NPTS 4096
#define HDIM 128
#define KNN 10
#define NSPLIT 4
#define CTILE 1024
#define SLOTS 12

typedef __attribute__((ext_vector_type(4))) float f32x4;
typedef __attribute__((ext_vector_type(4))) int   i32x4;
typedef __attribute__((ext_vector_type(8))) short s16x8;

__device__ __forceinline__ float relu_f(float x) { return x > 0.f ? x : 0.f; }
__device__ __forceinline__ float med3_f(float a, float b, float c) {
    return __builtin_amdgcn_fmed3f(a, b, c);
}
__device__ __forceinline__ unsigned bf16_rne(float f) {
    unsigned u = __float_as_uint(f);
    return (u + 0x7fffu + ((u >> 16) & 1u)) >> 16;
}
__device__ __forceinline__ float bf2f(unsigned h) { return __uint_as_float(h << 16); }

// ---------------------------------------------------------------- W pre-permute
// Converts 5 fp32 128x128 matrices (Wc[0..3], W1) into per-lane-permuted bf16
// hi/lo fragment layout: dword u of matrix m: kk=u>>11, ct=(u>>8)&7, l=(u>>2)&63,
// d=u&3 holds W[kk*32+(l>>4)*8+2d .. +1][ct*16+(l&15)] (even k in low half).
__global__ __launch_bounds__(256) void wprep(const float* __restrict__ Wc,
                                             const float* __restrict__ W1,
                                             unsigned* __restrict__ whi,
                                             unsigned* __restrict__ wlo)
{
    const int m = blockIdx.x;
    const float* W = (m < 4) ? (Wc + m * 16384) : W1;
    unsigned* oh = whi + m * 8192;
    unsigned* ol = wlo + m * 8192;
    for (int u = threadIdx.x; u < 8192; u += 256) {
        int kk = u >> 11, ct = (u >> 8) & 7, l = (u >> 2) & 63, d = u & 3;
        int k0 = kk * 32 + ((l >> 4) << 3) + 2 * d;
        int c  = ct * 16 + (l & 15);
        float f0 = W[k0 * 128 + c], f1 = W[(k0 + 1) * 128 + c];
        unsigned h0 = bf16_rne(f0), h1 = bf16_rne(f1);
        float r0 = f0 - bf2f(h0), r1 = f1 - bf2f(h1);
        oh[u] = h0 | (h1 << 16);
        ol[u] = bf16_rne(r0) | (bf16_rne(r1) << 16);
    }
}

// ---------------------------------------------------------------- KNN partial (R3 form)
__global__ __launch_bounds__(256) void knn_part(const float* __restrict__ pos,
                                                uint2* __restrict__ pdi)
{
    __shared__ float4 spt[CTILE];                      // 16 KB
    const int bid = blockIdx.x;
    const int s = bid & 3;
    const int chunk = (bid >> 2) & 15;
    const int b = bid >> 6;
    const float* pb = pos + (size_t)b * NPTS * 3;
    const int c0 = s << 10;

    for (int j = threadIdx.x; j < CTILE; j += 256) {
        int g = c0 + j;
        float x = pb[3 * g + 0], y = pb[3 * g + 1], z = pb[3 * g + 2];
        float sq = __fadd_rn(__fadd_rn(__fmul_rn(x, x), __fmul_rn(y, y)), __fmul_rn(z, z));
        spt[j] = make_float4(x, y, z, sq);
    }
    __syncthreads();

    const int i = chunk * 256 + threadIdx.x;
    const float qx = pb[3 * i + 0], qy = pb[3 * i + 1], qz = pb[3 * i + 2];
    const float qw = __fadd_rn(__fadd_rn(__fmul_rn(qx, qx), __fmul_rn(qy, qy)), __fmul_rn(qz, qz));

    float bd[KNN];
#pragma unroll
    for (int m = 0; m < KNN; ++m) bd[m] = INFINITY;

#pragma unroll 4
    for (int j = 0; j < CTILE; ++j) {
        float4 p = spt[j];
        float dot = __fadd_rn(__fadd_rn(__fmul_rn(qx, p.x), __fmul_rn(qy, p.y)),
                              __fmul_rn(qz, p.z));
        float d2 = __fsub_rn(__fadd_rn(qw, p.w), __fmul_rn(2.f, dot));
#pragma unroll
        for (int m = KNN - 1; m > 0; --m) bd[m] = med3_f(d2, bd[m - 1], bd[m]);
        bd[0] = fminf(d2, bd[0]);
    }
    const float thr = bd[KNN - 1];

    uint2* o = pdi + ((size_t)(b * NPTS + i) * NSPLIT + s) * SLOTS;
    int cnt = 0;
#pragma unroll 4
    for (int j = 0; j < CTILE; ++j) {
        float4 p = spt[j];
        float dot = __fadd_rn(__fadd_rn(__fmul_rn(qx, p.x), __fmul_rn(qy, p.y)),
                              __fmul_rn(qz, p.z));
        float d2 = __fsub_rn(__fadd_rn(qw, p.w), __fmul_rn(2.f, dot));
        if (d2 <= thr && cnt < SLOTS) {
            o[cnt] = make_uint2(__float_as_uint(d2), (unsigned)(c0 + j));
            ++cnt;
        }
    }
}

// ---------------------------------------------------------------- KNN merge
__global__ __launch_bounds__(256) void knn_merge(const uint2* __restrict__ pdi,
                                                 int* __restrict__ nbr)
{
    const int q = blockIdx.x * 256 + threadIdx.x;
    const uint2* in = pdi + (size_t)q * (NSPLIT * SLOTS);
    float bd[KNN];
    int   bi[KNN];
#pragma unroll
    for (int m = 0; m < KNN; ++m) { bd[m] = 3.4e38f; bi[m] = 0; }
#pragma unroll
    for (int u = 0; u < NSPLIT * SLOTS; ++u) {
        uint2 v = in[u];
        float d2 = __uint_as_float(v.x);
        int   ix = (int)v.y;
        if (d2 < bd[KNN - 1]) {
            bool c[KNN];
#pragma unroll
            for (int m = 0; m < KNN; ++m) c[m] = d2 < bd[m];
#pragma unroll
            for (int m = KNN - 1; m > 0; --m) {
                bd[m] = c[m] ? (c[m - 1] ? bd[m - 1] : d2) : bd[m];
                bi[m] = c[m] ? (c[m - 1] ? bi[m - 1] : ix) : bi[m];
            }
            bd[0] = c[0] ? d2 : bd[0];
            bi[0] = c[0] ? ix : bi[0];
        }
    }
    const int b = q >> 12;
    int* o = nbr + (size_t)q * KNN;
#pragma unroll
    for (int m = 0; m < KNN; ++m) o[m] = (b << 12) + bi[m];
}

// ---------------------------------------------------------------- x0 = relu(pos@W0+b0)
__global__ __launch_bounds__(256) void x0_kernel(const float* __restrict__ pos,
                                                 const float* __restrict__ W0,
                                                 const float* __restrict__ b0,
                                                 float* __restrict__ x0)
{
    int gid = blockIdx.x * 256 + threadIdx.x;
    int node = gid >> 5, qd = gid & 31;
    float px = pos[node * 3 + 0], py = pos[node * 3 + 1], pz = pos[node * 3 + 2];
    const float4 w0 = ((const float4*)W0)[qd];
    const float4 w1 = ((const float4*)W0)[32 + qd];
    const float4 w2 = ((const float4*)W0)[64 + qd];
    const float4 bb = ((const float4*)b0)[qd];
    float4 r;
    r.x = relu_f(fmaf(pz, w2.x, fmaf(py, w1.x, fmaf(px, w0.x, bb.x))));
    r.y = relu_f(fmaf(pz, w2.y, fmaf(py, w1.y, fmaf(px, w0.y, bb.y))));
    r.z = relu_f(fmaf(pz, w2.z, fmaf(py, w1.z, fmaf(px, w0.z, bb.z))));
    r.w = relu_f(fmaf(pz, w2.w, fmaf(py, w1.w, fmaf(px, w0.w, bb.w))));
    ((float4*)x0)[gid] = r;
}

// ---------------------------------------------------------------- MFMA GEMM step
// acc[ct] += hbf16x2(sh row-frag) @ Wfrag(ct) for one 32-wide K slab.
// Error-compensated: Ah*Bh + Al*Bh + Ah*Bl (neglected Al*Bl ~2^-18 rel).
__device__ __forceinline__ void gemm_kk(const float* shrow, const unsigned* sB,
                                        int l, f32x4* acc)
{
    float f[8];
#pragma unroll
    for (int j = 0; j < 8; ++j) f[j] = shrow[j];
    unsigned ah[4], al[4];
#pragma unroll
    for (int d = 0; d < 4; ++d) {
        unsigned h0 = bf16_rne(f[2 * d]), h1 = bf16_rne(f[2 * d + 1]);
        ah[d] = h0 | (h1 << 16);
        float r0 = f[2 * d] - bf2f(h0), r1 = f[2 * d + 1] - bf2f(h1);
        al[d] = bf16_rne(r0) | (bf16_rne(r1) << 16);
    }
    i32x4 ahv = { (int)ah[0], (int)ah[1], (int)ah[2], (int)ah[3] };
    i32x4 alv = { (int)al[0], (int)al[1], (int)al[2], (int)al[3] };
    s16x8 Ah = __builtin_bit_cast(s16x8, ahv);
    s16x8 Al = __builtin_bit_cast(s16x8, alv);
#pragma unroll
    for (int ct = 0; ct < 8; ++ct) {
        i32x4 bh = *(const i32x4*)&sB[(ct * 64 + l) * 4];
        i32x4 bl = *(const i32x4*)&sB[2048 + (ct * 64 + l) * 4];
        s16x8 Bh = __builtin_bit_cast(s16x8, bh);
        s16x8 Bl = __builtin_bit_cast(s16x8, bl);
        acc[ct] = __builtin_amdgcn_mfma_f32_16x16x32_bf16(Ah, Bh, acc[ct], 0, 0, 0);
        acc[ct] = __builtin_amdgcn_mfma_f32_16x16x32_bf16(Al, Bh, acc[ct], 0, 0, 0);
        acc[ct] = __builtin_amdgcn_mfma_f32_16x16x32_bf16(Ah, Bl, acc[ct], 0, 0, 0);
    }
}

// ---------------------------------------------------------------- fused GCN2 layer (MFMA)
__global__ __launch_bounds__(256) void gcn_layer(const float* __restrict__ xin,
                                                 float* __restrict__ xout,
                                                 const float* __restrict__ pos,
                                                 const float* __restrict__ W0,
                                                 const float* __restrict__ b0,
                                                 const unsigned* __restrict__ whi,
                                                 const unsigned* __restrict__ wlo,
                                                 const int* __restrict__ nbr,
                                                 float omb, float beta)
{
    __shared__ float sh[64][129];                      // 33,024 B fp32 h (residual + A src)
    __shared__ __align__(16) unsigned sB[4096];        // 16 KB: hi[2048] | lo[2048] per kk
    __shared__ float sW0[512];
    const int t = threadIdx.x;
    const int bid = blockIdx.x;
    const int swz = (bid & 7) * 128 + (bid >> 3);      // XCD-chunked, bijective
    const int node0 = swz * 64;

    if (t < 128) {
        sW0[t] = W0[t]; sW0[128 + t] = W0[128 + t];
        sW0[256 + t] = W0[256 + t]; sW0[384 + t] = b0[t];
    }
    __syncthreads();

    const float4* xin4 = (const float4*)xin;
    for (int u = t; u < 64 * 32; u += 256) {           // gather + residual -> sh
        int n = u >> 5, qd = u & 31;
        int node = node0 + n;
        float ax = 0.f, ay = 0.f, az = 0.f, aw = 0.f;
        const int* nb = nbr + node * KNN;
#pragma unroll
        for (int k = 0; k < KNN; ++k) {
            float4 v = xin4[nb[k] * 32 + qd];
            ax += v.x; ay += v.y; az += v.z; aw += v.w;
        }
        float px = pos[node * 3 + 0], py = pos[node * 3 + 1], pz = pos[node * 3 + 2];
        int c = qd * 4;
        sh[n][c + 0] = fmaf(0.9f, ax, 0.1f * relu_f(fmaf(pz, sW0[256 + c + 0], fmaf(py, sW0[128 + c + 0], fmaf(px, sW0[c + 0], sW0[384 + c + 0])))));
        sh[n][c + 1] = fmaf(0.9f, ay, 0.1f * relu_f(fmaf(pz, sW0[256 + c + 1], fmaf(py, sW0[128 + c + 1], fmaf(px, sW0[c + 1], sW0[384 + c + 1])))));
        sh[n][c + 2] = fmaf(0.9f, az, 0.1f * relu_f(fmaf(pz, sW0[256 + c + 2], fmaf(py, sW0[128 + c + 2], fmaf(px, sW0[c + 2], sW0[384 + c + 2])))));
        sh[n][c + 3] = fmaf(0.9f, aw, 0.1f * relu_f(fmaf(pz, sW0[256 + c + 3], fmaf(py, sW0[128 + c + 3], fmaf(px, sW0[c + 3], sW0[384 + c + 3])))));
    }

    const int w = t >> 6, l = t & 63, lr = l & 15, lg = l >> 4;
    f32x4 acc[8];
    const f32x4 z4 = { 0.f, 0.f, 0.f, 0.f };
#pragma unroll
    for (int ct = 0; ct < 8; ++ct) acc[ct] = z4;

    for (int kk = 0; kk < 4; ++kk) {
        __syncthreads();                               // sB free + (kk=0) sh ready
        const uint4* srch = (const uint4*)(whi + kk * 2048);
        const uint4* srcl = (const uint4*)(wlo + kk * 2048);
        uint4* dst = (uint4*)sB;
        dst[t] = srch[t];           dst[256 + t] = srch[256 + t];
        dst[512 + t] = srcl[t];     dst[768 + t] = srcl[256 + t];
        __syncthreads();
        gemm_kk(&sh[w * 16 + lr][kk * 32 + lg * 8], sB, l, acc);
    }

    // epilogue: out = relu(omb*h + beta*(h@W));  D layout: col=lane&15, row=(lane>>4)*4+r
#pragma unroll
    for (int ct = 0; ct < 8; ++ct) {
        int col = ct * 16 + lr;
#pragma unroll
        for (int r = 0; r < 4; ++r) {
            int rw = w * 16 + lg * 4 + r;
            float h = sh[rw][col];
            xout[(size_t)(node0 + rw) * HDIM + col] = relu_f(fmaf(omb, h, beta * acc[ct][r]));
        }
    }
}

// ---------------------------------------------------------------- x@W1+b1 then global max-pool (MFMA)
__global__ __launch_bounds__(256) void w1pool_kernel(const float* __restrict__ xin,
                                                     const unsigned* __restrict__ whi,
                                                     const unsigned* __restrict__ wlo,
                                                     const float* __restrict__ b1,
                                                     unsigned int* __restrict__ pool)
{
    __shared__ float sh[64][129];
    __shared__ __align__(16) unsigned sB[4096];
    __shared__ float smax[16][128];
    const int t = threadIdx.x;
    const int bid = blockIdx.x;
    const int swz = (bid & 7) * 128 + (bid >> 3);
    const int node0 = swz * 64;

    const float4* xin4 = (const float4*)xin;
    for (int u = t; u < 64 * 32; u += 256) {
        int n = u >> 5, qd = u & 31;
        float4 v = xin4[(node0 + n) * 32 + qd];
        int c = qd * 4;
        sh[n][c + 0] = v.x; sh[n][c + 1] = v.y; sh[n][c + 2] = v.z; sh[n][c + 3] = v.w;
    }

    const int w = t >> 6, l = t & 63, lr = l & 15, lg = l >> 4;
    f32x4 acc[8];
    const f32x4 z4 = { 0.f, 0.f, 0.f, 0.f };
#pragma unroll
    for (int ct = 0; ct < 8; ++ct) acc[ct] = z4;

    for (int kk = 0; kk < 4; ++kk) {
        __syncthreads();
        const uint4* srch = (const uint4*)(whi + kk * 2048);
        const uint4* srcl = (const uint4*)(wlo + kk * 2048);
        uint4* dst = (uint4*)sB;
        dst[t] = srch[t];           dst[256 + t] = srch[256 + t];
        dst[512 + t] = srcl[t];     dst[768 + t] = srcl[256 + t];
        __syncthreads();
        gemm_kk(&sh[w * 16 + lr][kk * 32 + lg * 8], sB, l, acc);
    }

    // per-thread max over its 4 rows per column tile, + bias
#pragma unroll
    for (int ct = 0; ct < 8; ++ct) {
        int col = ct * 16 + lr;
        float m = fmaxf(fmaxf(acc[ct][0], acc[ct][1]), fmaxf(acc[ct][2], acc[ct][3]));
        smax[w * 4 + lg][col] = m + b1[col];
    }
    __syncthreads();
    if (t < 128) {
        float m = smax[0][t];
#pragma unroll
        for (int r = 1; r < 16; ++r) m = fmaxf(m, smax[r][t]);
        unsigned int u = __float_as_uint(m);
        unsigned int key = (u & 0x80000000u) ? ~u : (u | 0x80000000u);
        atomicMax(&pool[(node0 >> 12) * HDIM + t], key);
    }
}

// ---------------------------------------------------------------- MLP head (1 block)
__global__ __launch_bounds__(256) void head_kernel(const unsigned int* __restrict__ pool,
                                                   const float* __restrict__ Wm1, const float* __restrict__ bm1,
                                                   const float* __restrict__ g1,  const float* __restrict__ be1,
                                                   const float* __restrict__ Wm2, const float* __restrict__ bm2,
                                                   const float* __restrict__ g2,  const float* __restrict__ be2,
                                                   const float* __restrict__ Wout,const float* __restrict__ bout,
                                                   float* __restrict__ out)
{
    __shared__ float sA[16][128];
    __shared__ float sB2[16][128];
    __shared__ float sL[16][10];
    const int t = threadIdx.x;
    for (int u = t; u < 2048; u += 256) {
        unsigned int k = pool[u];
        unsigned int orig = (k & 0x80000000u) ? (k ^ 0x80000000u) : ~k;
        sA[u >> 7][u & 127] = __uint_as_float(orig);
    }
    __syncthreads();

    if (t < 128) {
        float y[16];
#pragma unroll
        for (int b = 0; b < 16; ++b) y[b] = bm1[t];
        for (int i = 0; i < 128; ++i) {
            float w = Wm1[i * 128 + t];
#pragma unroll
            for (int b = 0; b < 16; ++b) y[b] = fmaf(sA[b][i], w, y[b]);
        }
        float mu = 0.f;
#pragma unroll
        for (int b = 0; b < 16; ++b) mu += y[b];
        mu *= (1.f / 16.f);
        float var = 0.f;
#pragma unroll
        for (int b = 0; b < 16; ++b) { float d = y[b] - mu; var = fmaf(d, d, var); }
        var *= (1.f / 16.f);
        float sc = g1[t] / sqrtf(var + 1e-5f);
        float sb = be1[t];
#pragma unroll
        for (int b = 0; b < 16; ++b) sB2[b][t] = relu_f((y[b] - mu) * sc + sb);
    }
    __syncthreads();

    if (t < 128) {
        float y[16];
#pragma unroll
        for (int b = 0; b < 16; ++b) y[b] = bm2[t];
        for (int i = 0; i < 128; ++i) {
            float w = Wm2[i * 128 + t];
#pragma unroll
            for (int b = 0; b < 16; ++b) y[b] = fmaf(sB2[b][i], w, y[b]);
        }
        float mu = 0.f;
#pragma unroll
        for (int b = 0; b < 16; ++b) mu += y[b];
        mu *= (1.f / 16.f);
        float var = 0.f;
#pragma unroll
        for (int b = 0; b < 16; ++b) { float d = y[b] - mu; var = fmaf(d, d, var); }
        var *= (1.f / 16.f);
        float sc = g2[t] / sqrtf(var + 1e-5f);
        float sb = be2[t];
#pragma unroll
        for (int b = 0; b < 16; ++b) sA[b][t] = relu_f((y[b] - mu) * sc + sb);
    }
    __syncthreads();

    if (t < 160) {
        int b = t / 10, o = t % 10;
        float a = bout[o];
        for (int i = 0; i < 128; ++i) a = fmaf(sA[b][i], Wout[i * 10 + o], a);
        sL[b][o] = a;
    }
    __syncthreads();

    if (t < 16) {
        float m = sL[t][0];
#pragma unroll
        for (int o = 1; o < 10; ++o) m = fmaxf(m, sL[t][o]);
        float s = 0.f;
#pragma unroll
        for (int o = 0; o < 10; ++o) s += expf(sL[t][o] - m);
        float ls = logf(s);
#pragma unroll
        for (int o = 0; o < 10; ++o) out[t * 10 + o] = sL[t][o] - m - ls;
    }
}

// ----------------------------------------------------------------
extern "C" void kernel_launch(void* const* d_in, const int* in_sizes, int n_in,
                              void* d_out, int out_size, void* d_ws, size_t ws_size,
                              hipStream_t stream)
{
    const float* pos = (const float*)d_in[0];
    const float* W0  = (const float*)d_in[1];
    const float* b0  = (const float*)d_in[2];
    const float* Wc  = (const float*)d_in[3];
    const float* W1  = (const float*)d_in[4];
    const float* b1  = (const float*)d_in[5];
    const float* Wm1 = (const float*)d_in[6];
    const float* bm1 = (const float*)d_in[7];
    const float* g1  = (const float*)d_in[8];
    const float* be1 = (const float*)d_in[9];
    const float* Wm2 = (const float*)d_in[10];
    const float* bm2 = (const float*)d_in[11];
    const float* g2  = (const float*)d_in[12];
    const float* be2 = (const float*)d_in[13];
    const float* Wout= (const float*)d_in[14];
    const float* bout= (const float*)d_in[15];
    float* out = (float*)d_out;

    char* ws = (char*)d_ws;
    float*        xA   = (float*)ws;                       // 33,554,432 B
    float*        xB   = (float*)(ws + 33554432);          // 33,554,432 B
    int*          nbr  = (int*)(ws + 67108864);            //  2,621,440 B
    unsigned int* pool = (unsigned int*)(ws + 69730304);   //      8,192 B
    unsigned*     whi  = (unsigned*)(ws + 69738496);       //    163,840 B (5 x 8192 dwords)
    unsigned*     wlo  = (unsigned*)(ws + 69902336);       //    163,840 B
    // KNN hit buffer: needed only before x0 writes xA -> alias onto xA.
    uint2* pdi = (uint2*)ws;                               // 25,165,824 B

    hipMemsetAsync(pdi, 0xFF, (size_t)16 * NPTS * NSPLIT * SLOTS * 8, stream); // NaN prefill
    wprep<<<5, 256, 0, stream>>>(Wc, W1, whi, wlo);
    knn_part<<<1024, 256, 0, stream>>>(pos, pdi);
    knn_merge<<<256, 256, 0, stream>>>(pdi, nbr);
    x0_kernel<<<8192, 256, 0, stream>>>(pos, W0, b0, xA);

    const float betas[4] = { 0.40546510810816438f, 0.22314355131420976f,
                             0.15415067982725836f, 0.11778303565638346f };
    gcn_layer<<<1024, 256, 0, stream>>>(xA, xB, pos, W0, b0, whi + 0 * 8192, wlo + 0 * 8192, nbr, 1.f - betas[0], betas[0]);
    gcn_layer<<<1024, 256, 0, stream>>>(xB, xA, pos, W0, b0, whi + 1 * 8192, wlo + 1 * 8192, nbr, 1.f - betas[1], betas[1]);
    gcn_layer<<<1024, 256, 0, stream>>>(xA, xB, pos, W0, b0, whi + 2 * 8192, wlo + 2 * 8192, nbr, 1.f - betas[2], betas[2]);
    gcn_layer<<<1024, 256, 0, stream>>>(xB, xA, pos, W0, b0, whi + 3 * 8192, wlo + 3 * 8192, nbr, 1.f - betas[3], betas[3]);

    hipMemsetAsync(pool, 0, 16 * HDIM * sizeof(unsigned int), stream);
    w1pool_kernel<<<1024, 256, 0, stream>>>(xA, whi + 4 * 8192, wlo + 4 * 8192, b1, pool);
    head_kernel<<<1, 256, 0, stream>>>(pool, Wm1, bm1, g1, be1, Wm2, bm2, g2, be2, Wout, bout, out);
}